// Round 1
// baseline (101.851 us; speedup 1.0000x reference)
//
#include <hip/hip_runtime.h>

// Problem constants (B, N_NODE, FN, FE) = (8, 128, 64, 64)
#define NB 8
#define NNODE 128
#define NF 64

typedef _Float16 half8 __attribute__((ext_vector_type(8)));
typedef float floatx4 __attribute__((ext_vector_type(4)));

// ws layout: P[0]=Pi_att, P[1]=Pj_att, P[2]=Pi_nei, P[3]=Pj_nei; each [B*N][64] f32
#define PSTR (NB * NNODE * NF) // 65536 floats per array

// Kernel 1: per-node projections Pi = H@W[:64], Pj = H@W[64:128] for both branches.
// Also zeroes d_out (it is poisoned 0xAA before every launch; main kernel atomicAdds).
__global__ __launch_bounds__(256)
void proj_kernel(const float* __restrict__ H, const float* __restrict__ Wa,
                 const float* __restrict__ Wn, float* __restrict__ P,
                 float* __restrict__ out_zero) {
  int idx = blockIdx.x * 256 + threadIdx.x; // 0..65535 ; wave = one node, lanes = l
  int l = idx & 63;
  int node = idx >> 6; // b*N + n
  const float* h = H + node * 64;
  float pia = 0.f, pja = 0.f, pin = 0.f, pjn = 0.f;
#pragma unroll 4
  for (int f = 0; f < 64; ++f) {
    float hv = h[f]; // wave-uniform broadcast, L1-served
    pia += hv * Wa[f * 64 + l];
    pja += hv * Wa[(64 + f) * 64 + l];
    pin += hv * Wn[f * 64 + l];
    pjn += hv * Wn[(64 + f) * 64 + l];
  }
  int off = node * 64 + l;
  P[off] = pia;
  P[PSTR + off] = pja;
  P[2 * PSTR + off] = pin;
  P[3 * PSTR + off] = pjn;
  out_zero[idx] = 0.f;
}

// Main kernel: grid 512 blocks x 256 threads (4 waves).
// Wave owns (b, j-tile of 16, i-chunk of 4), all 64 l.
// Per i: proj = E[b,i,jtile,:] @ We (MFMA, K=64 = 2x 16x16x32_f16 per l-tile)
//        + Pi[i,l] + Pj[j,l];  branch = A[b,i,j]*proj + bias;
//        acc += sigmoid(att)*relu(conv);  epilogue: atomicAdd into out[b,j,l].
__global__ __launch_bounds__(256, 2)
void amp_main(const float* __restrict__ A, const float* __restrict__ E,
              const float* __restrict__ Wa, const float* __restrict__ Wn,
              const float* __restrict__ ba, const float* __restrict__ bn,
              const float* __restrict__ P, float* __restrict__ out) {
  const int bx = blockIdx.x;  // 0..511
  const int b = bx >> 6;      // 0..7
  const int rem = bx & 63;
  const int jt = rem >> 3;    // 0..7  (j tile)
  const int c8 = rem & 7;     // 0..7  (i chunk group)
  const int w = threadIdx.x >> 6;   // wave in block
  const int lane = threadIdx.x & 63;
  const int quad = lane >> 4;
  const int l15 = lane & 15;
  const int i0 = (c8 * 4 + w) * 4;  // 4 i's per wave
  const int j0 = jt * 16;

  // Loop-invariant B-fragments: We[k=e][n=l], lane holds k=quad*8+x (+32 for khalf 1),
  // n = t*16 + l15.  wf[branch][ltile][khalf]
  half8 wf[2][4][2];
  const float* Wptr[2] = {Wa, Wn};
#pragma unroll
  for (int br = 0; br < 2; ++br)
#pragma unroll
    for (int t = 0; t < 4; ++t)
#pragma unroll
      for (int hh = 0; hh < 2; ++hh) {
        const float* wsrc = Wptr[br] + (128 + hh * 32 + quad * 8) * 64 + t * 16 + l15;
        half8 v;
#pragma unroll
        for (int x = 0; x < 8; ++x) v[x] = (_Float16)wsrc[x * 64];
        wf[br][t][hh] = v;
      }

  // Loop-invariant Pj values in C-layout positions: row j = j0+quad*4+r, col l = t*16+l15
  float pj[2][4][4];
#pragma unroll
  for (int br = 0; br < 2; ++br) {
    const float* psrc = P + (br ? 3 * PSTR : PSTR) + (b * 128 + j0) * 64;
#pragma unroll
    for (int t = 0; t < 4; ++t)
#pragma unroll
      for (int r = 0; r < 4; ++r)
        pj[br][t][r] = psrc[(quad * 4 + r) * 64 + t * 16 + l15];
  }
  float biasv[2][4];
#pragma unroll
  for (int t = 0; t < 4; ++t) {
    biasv[0][t] = ba[t * 16 + l15];
    biasv[1][t] = bn[t * 16 + l15];
  }

  float acc[4][4];
#pragma unroll
  for (int t = 0; t < 4; ++t)
#pragma unroll
    for (int r = 0; r < 4; ++r) acc[t][r] = 0.f;

  for (int ii = 0; ii < 4; ++ii) {
    const int i = i0 + ii;
    // A-fragment: A[m=lane&15][k=quad*8+x] -> row j0+l15 of E tile, e = quad*8+x (+32)
    const float* erow = E + ((size_t)((b * 128 + i) * 128 + j0 + l15)) * 64 + quad * 8;
    const float4 e0 = *reinterpret_cast<const float4*>(erow);
    const float4 e1 = *reinterpret_cast<const float4*>(erow + 4);
    const float4 e2 = *reinterpret_cast<const float4*>(erow + 32);
    const float4 e3 = *reinterpret_cast<const float4*>(erow + 36);
    half8 a0, a1;
    a0[0] = (_Float16)e0.x; a0[1] = (_Float16)e0.y; a0[2] = (_Float16)e0.z; a0[3] = (_Float16)e0.w;
    a0[4] = (_Float16)e1.x; a0[5] = (_Float16)e1.y; a0[6] = (_Float16)e1.z; a0[7] = (_Float16)e1.w;
    a1[0] = (_Float16)e2.x; a1[1] = (_Float16)e2.y; a1[2] = (_Float16)e2.z; a1[3] = (_Float16)e2.w;
    a1[4] = (_Float16)e3.x; a1[5] = (_Float16)e3.y; a1[6] = (_Float16)e3.z; a1[7] = (_Float16)e3.w;

    float pia[4], pin[4];
    const float* pisrc = P + (b * 128 + i) * 64;
#pragma unroll
    for (int t = 0; t < 4; ++t) {
      pia[t] = pisrc[t * 16 + l15];
      pin[t] = pisrc[2 * PSTR + t * 16 + l15];
    }
    float av[4];
    const float* arow = A + (b * 128 + i) * 128 + j0 + quad * 4;
#pragma unroll
    for (int r = 0; r < 4; ++r) av[r] = arow[r];

#pragma unroll
    for (int t = 0; t < 4; ++t) {
      floatx4 z = {0.f, 0.f, 0.f, 0.f};
      floatx4 pa = __builtin_amdgcn_mfma_f32_16x16x32_f16(a0, wf[0][t][0], z, 0, 0, 0);
      pa = __builtin_amdgcn_mfma_f32_16x16x32_f16(a1, wf[0][t][1], pa, 0, 0, 0);
      floatx4 pn = __builtin_amdgcn_mfma_f32_16x16x32_f16(a0, wf[1][t][0], z, 0, 0, 0);
      pn = __builtin_amdgcn_mfma_f32_16x16x32_f16(a1, wf[1][t][1], pn, 0, 0, 0);
#pragma unroll
      for (int r = 0; r < 4; ++r) {
        float att = av[r] * (pa[r] + pia[t] + pj[0][t][r]) + biasv[0][t];
        float cnv = av[r] * (pn[r] + pin[t] + pj[1][t][r]) + biasv[1][t];
        float ex = __expf(-att);
        float sig = __builtin_amdgcn_rcpf(1.0f + ex);
        acc[t][r] += sig * fmaxf(cnv, 0.f);
      }
    }
  }

  float* obase = out + (b * 128 + j0 + quad * 4) * 64;
#pragma unroll
  for (int t = 0; t < 4; ++t)
#pragma unroll
    for (int r = 0; r < 4; ++r)
      atomicAdd(obase + r * 64 + t * 16 + l15, acc[t][r]);
}

extern "C" void kernel_launch(void* const* d_in, const int* in_sizes, int n_in,
                              void* d_out, int out_size, void* d_ws, size_t ws_size,
                              hipStream_t stream) {
  const float* H = (const float*)d_in[0];
  const float* A = (const float*)d_in[1];
  const float* E = (const float*)d_in[2];
  const float* Wa = (const float*)d_in[3];
  const float* Wn = (const float*)d_in[4];
  const float* ba = (const float*)d_in[5];
  const float* bn = (const float*)d_in[6];
  float* out = (float*)d_out;
  float* P = (float*)d_ws; // 4 * 65536 floats = 1 MB

  proj_kernel<<<256, 256, 0, stream>>>(H, Wa, Wn, P, out);
  amp_main<<<512, 256, 0, stream>>>(A, E, Wa, Wn, ba, bn, P, out);
}

// Round 2
// 99.882 us; speedup vs baseline: 1.0197x; 1.0197x over previous
//
#include <hip/hip_runtime.h>

// Problem constants (B, N_NODE, FN, FE) = (8, 128, 64, 64)
#define NB 8
#define NNODE 128
#define NF 64

typedef _Float16 half8 __attribute__((ext_vector_type(8)));
typedef float floatx4 __attribute__((ext_vector_type(4)));

// ws layout: P[0]=Pi_att, P[1]=Pj_att, P[2]=Pi_nei, P[3]=Pj_nei; each [B*N][64] f32
#define PSTR (NB * NNODE * NF) // 65536 floats per array

// Kernel 1: per-node projections Pi = H@W[:64], Pj = H@W[64:128] for both branches.
// Also zeroes d_out (poisoned 0xAA before every launch; main kernel atomicAdds).
__global__ __launch_bounds__(256)
void proj_kernel(const float* __restrict__ H, const float* __restrict__ Wa,
                 const float* __restrict__ Wn, float* __restrict__ P,
                 float* __restrict__ out_zero) {
  int idx = blockIdx.x * 256 + threadIdx.x; // 0..65535 ; wave = one node, lanes = l
  int l = idx & 63;
  int node = idx >> 6; // b*N + n
  const float* h = H + node * 64;
  float pia = 0.f, pja = 0.f, pin = 0.f, pjn = 0.f;
#pragma unroll 8
  for (int f = 0; f < 64; ++f) {
    float hv = h[f]; // wave-uniform broadcast, L1/L2-served
    pia += hv * Wa[f * 64 + l];
    pja += hv * Wa[(64 + f) * 64 + l];
    pin += hv * Wn[f * 64 + l];
    pjn += hv * Wn[(64 + f) * 64 + l];
  }
  int off = node * 64 + l;
  P[off] = pia;
  P[PSTR + off] = pja;
  P[2 * PSTR + off] = pin;
  P[3 * PSTR + off] = pjn;
  out_zero[idx] = 0.f;
}

// Main kernel: grid 512 blocks x 256 threads (4 waves).
// Block owns (b, j-tile of 16, chunk of 16 i's); wave w takes 4 of those i's.
// Per i: proj = E[b,i,jtile,:] @ We (MFMA, K=64 = 2x 16x16x32_f16 per l-tile)
//        + Pi[i,l] + Pj[j,l];  branch = A[b,i,j]*proj + bias;
//        acc += sigmoid(att)*relu(conv).
// Epilogue: LDS-reduce the 4 waves, then 4 coalesced atomicAdds per thread
// (524K atomics total, 8 contenders/address — vs 2.1M / 32 in R1).
__global__ __launch_bounds__(256, 2)
void amp_main(const float* __restrict__ A, const float* __restrict__ E,
              const float* __restrict__ Wa, const float* __restrict__ Wn,
              const float* __restrict__ ba, const float* __restrict__ bn,
              const float* __restrict__ P, float* __restrict__ out) {
  const int bx = blockIdx.x;  // 0..511
  const int b = bx >> 6;      // 0..7
  const int rem = bx & 63;
  const int jt = rem >> 3;    // 0..7  (j tile)
  const int ch = rem & 7;     // 0..7  (i chunk of 16)
  const int w = threadIdx.x >> 6;   // wave in block
  const int lane = threadIdx.x & 63;
  const int quad = lane >> 4;
  const int l15 = lane & 15;
  const int i0 = ch * 16 + w * 4;   // 4 i's per wave
  const int j0 = jt * 16;

  // Loop-invariant B-fragments: We[k=e][n=l]; lane holds k=quad*8+x (+32 for khalf 1),
  // n = t*16 + l15.  wf[branch][ltile][khalf]
  half8 wf[2][4][2];
  const float* Wptr[2] = {Wa, Wn};
#pragma unroll
  for (int br = 0; br < 2; ++br)
#pragma unroll
    for (int t = 0; t < 4; ++t)
#pragma unroll
      for (int hh = 0; hh < 2; ++hh) {
        const float* wsrc = Wptr[br] + (128 + hh * 32 + quad * 8) * 64 + t * 16 + l15;
        half8 v;
#pragma unroll
        for (int x = 0; x < 8; ++x) v[x] = (_Float16)wsrc[x * 64];
        wf[br][t][hh] = v;
      }

  // Loop-invariant Pj in C-layout positions: row j = j0+quad*4+r, col l = t*16+l15
  float pj[2][4][4];
#pragma unroll
  for (int br = 0; br < 2; ++br) {
    const float* psrc = P + (br ? 3 * PSTR : PSTR) + (b * 128 + j0) * 64;
#pragma unroll
    for (int t = 0; t < 4; ++t)
#pragma unroll
      for (int r = 0; r < 4; ++r)
        pj[br][t][r] = psrc[(quad * 4 + r) * 64 + t * 16 + l15];
  }
  float biasv[2][4];
#pragma unroll
  for (int t = 0; t < 4; ++t) {
    biasv[0][t] = ba[t * 16 + l15];
    biasv[1][t] = bn[t * 16 + l15];
  }

  float acc[4][4];
#pragma unroll
  for (int t = 0; t < 4; ++t)
#pragma unroll
    for (int r = 0; r < 4; ++r) acc[t][r] = 0.f;

#pragma unroll   // full unroll: all 16 E float4 loads issue up front (latency hiding)
  for (int ii = 0; ii < 4; ++ii) {
    const int i = i0 + ii;
    // A-fragment: A[m=lane&15][k=quad*8+x] -> row j0+l15 of E tile, e = quad*8+x (+32)
    const float* erow = E + ((size_t)((b * 128 + i) * 128 + j0 + l15)) * 64 + quad * 8;
    const float4 e0 = *reinterpret_cast<const float4*>(erow);
    const float4 e1 = *reinterpret_cast<const float4*>(erow + 4);
    const float4 e2 = *reinterpret_cast<const float4*>(erow + 32);
    const float4 e3 = *reinterpret_cast<const float4*>(erow + 36);
    half8 a0, a1;
    a0[0] = (_Float16)e0.x; a0[1] = (_Float16)e0.y; a0[2] = (_Float16)e0.z; a0[3] = (_Float16)e0.w;
    a0[4] = (_Float16)e1.x; a0[5] = (_Float16)e1.y; a0[6] = (_Float16)e1.z; a0[7] = (_Float16)e1.w;
    a1[0] = (_Float16)e2.x; a1[1] = (_Float16)e2.y; a1[2] = (_Float16)e2.z; a1[3] = (_Float16)e2.w;
    a1[4] = (_Float16)e3.x; a1[5] = (_Float16)e3.y; a1[6] = (_Float16)e3.z; a1[7] = (_Float16)e3.w;

    float pia[4], pin[4];
    const float* pisrc = P + (b * 128 + i) * 64;
#pragma unroll
    for (int t = 0; t < 4; ++t) {
      pia[t] = pisrc[t * 16 + l15];
      pin[t] = pisrc[2 * PSTR + t * 16 + l15];
    }
    const float4 av4 = *reinterpret_cast<const float4*>(
        A + (b * 128 + i) * 128 + j0 + quad * 4);
    const float av[4] = {av4.x, av4.y, av4.z, av4.w};

#pragma unroll
    for (int t = 0; t < 4; ++t) {
      floatx4 z = {0.f, 0.f, 0.f, 0.f};
      floatx4 pa = __builtin_amdgcn_mfma_f32_16x16x32_f16(a0, wf[0][t][0], z, 0, 0, 0);
      pa = __builtin_amdgcn_mfma_f32_16x16x32_f16(a1, wf[0][t][1], pa, 0, 0, 0);
      floatx4 pn = __builtin_amdgcn_mfma_f32_16x16x32_f16(a0, wf[1][t][0], z, 0, 0, 0);
      pn = __builtin_amdgcn_mfma_f32_16x16x32_f16(a1, wf[1][t][1], pn, 0, 0, 0);
#pragma unroll
      for (int r = 0; r < 4; ++r) {
        float att = av[r] * (pa[r] + pia[t] + pj[0][t][r]) + biasv[0][t];
        float cnv = av[r] * (pn[r] + pin[t] + pj[1][t][r]) + biasv[1][t];
        float ex = __expf(-att);
        float sig = __builtin_amdgcn_rcpf(1.0f + ex);
        acc[t][r] += sig * fmaxf(cnv, 0.f);
      }
    }
  }

  // Intra-block reduction: 4 waves -> 1 partial per (j_local, l), then atomics.
  __shared__ float red[4][16][64];
#pragma unroll
  for (int t = 0; t < 4; ++t)
#pragma unroll
    for (int r = 0; r < 4; ++r)
      red[w][quad * 4 + r][t * 16 + l15] = acc[t][r];
  __syncthreads();

  const int tid = threadIdx.x;
#pragma unroll
  for (int k = 0; k < 4; ++k) {
    int idx = k * 256 + tid;       // 0..1023 over the 16x64 out tile
    int jl = idx >> 6;
    int l = idx & 63;
    float s = red[0][jl][l] + red[1][jl][l] + red[2][jl][l] + red[3][jl][l];
    atomicAdd(out + (b * 128 + j0 + jl) * 64 + l, s);
  }
}

extern "C" void kernel_launch(void* const* d_in, const int* in_sizes, int n_in,
                              void* d_out, int out_size, void* d_ws, size_t ws_size,
                              hipStream_t stream) {
  const float* H = (const float*)d_in[0];
  const float* A = (const float*)d_in[1];
  const float* E = (const float*)d_in[2];
  const float* Wa = (const float*)d_in[3];
  const float* Wn = (const float*)d_in[4];
  const float* ba = (const float*)d_in[5];
  const float* bn = (const float*)d_in[6];
  float* out = (float*)d_out;
  float* P = (float*)d_ws; // 4 * 65536 floats = 1 MB

  proj_kernel<<<256, 256, 0, stream>>>(H, Wa, Wn, P, out);
  amp_main<<<512, 256, 0, stream>>>(A, E, Wa, Wn, ba, bn, P, out);
}

// Round 3
// 99.339 us; speedup vs baseline: 1.0253x; 1.0055x over previous
//
#include <hip/hip_runtime.h>

// Problem constants (B, N_NODE, FN, FE) = (8, 128, 64, 64)
// Single fused kernel: each block (b, j-tile16, i-chunk16) recomputes its own
// node projections Pi=H@W[:64], Pj=H@W[64:128] via prologue MFMAs (no proj
// kernel, no P workspace round-trip), then runs the E@We main loop.
//   out[b,j,l] = sum_i sigmoid(att)*relu(conv),
//   att/conv = A[b,i,j]*(Pi[i,l]+Pj[j,l]+(E@We)[b,i,j,l]) + bias

typedef _Float16 half8 __attribute__((ext_vector_type(8)));
typedef float floatx4 __attribute__((ext_vector_type(4)));

__device__ __forceinline__ half8 cvt2(const float4 a, const float4 b) {
  half8 v;
  v[0] = (_Float16)a.x; v[1] = (_Float16)a.y; v[2] = (_Float16)a.z; v[3] = (_Float16)a.w;
  v[4] = (_Float16)b.x; v[5] = (_Float16)b.y; v[6] = (_Float16)b.z; v[7] = (_Float16)b.w;
  return v;
}

__global__ __launch_bounds__(256, 2)
void amp_fused(const float* __restrict__ H, const float* __restrict__ A,
               const float* __restrict__ E,
               const float* __restrict__ Wa, const float* __restrict__ Wn,
               const float* __restrict__ ba, const float* __restrict__ bn,
               float* __restrict__ out) {
  const int bx = blockIdx.x;  // 0..511
  const int b = bx >> 6;      // 0..7
  const int rem = bx & 63;
  const int jt = rem >> 3;    // 0..7  j tile of 16
  const int ch = rem & 7;     // 0..7  i chunk of 16
  const int w = threadIdx.x >> 6;   // wave in block
  const int lane = threadIdx.x & 63;
  const int quad = lane >> 4;
  const int l15 = lane & 15;
  const int i0b = ch * 16;          // block's i chunk base
  const int i0 = i0b + w * 4;       // this wave's 4 i's
  const int j0 = jt * 16;
  const float* Wptr[2] = {Wa, Wn};

  // ---- Prologue: H fragments (A-operand layout: row=l15, k=quad*8+x+hh*32) ----
  half8 hi[2], hj[2];
  {
    const float* hib = H + (b * 128 + i0b + l15) * 64 + quad * 8;
    const float* hjb = H + (b * 128 + j0 + l15) * 64 + quad * 8;
#pragma unroll
    for (int hh = 0; hh < 2; ++hh) {
      hi[hh] = cvt2(*reinterpret_cast<const float4*>(hib + hh * 32),
                    *reinterpret_cast<const float4*>(hib + hh * 32 + 4));
      hj[hh] = cvt2(*reinterpret_cast<const float4*>(hjb + hh * 32),
                    *reinterpret_cast<const float4*>(hjb + hh * 32 + 4));
    }
  }

  // Pi redistributed per-wave (pia_all[br][t][ii]); Pj stays in C-layout (pj[br][t][r]).
  float pia_all[2][4][4];
  float pj[2][4][4];
  for (int br = 0; br < 2; ++br) {
    const float* W = Wptr[br];
#pragma unroll
    for (int t = 0; t < 4; ++t) {
      floatx4 z = {0.f, 0.f, 0.f, 0.f};
      floatx4 pif = z, pjf = z;
#pragma unroll
      for (int hh = 0; hh < 2; ++hh) {
        const float* wi = W + (hh * 32 + quad * 8) * 64 + t * 16 + l15;        // Wi rows 0..63
        const float* wj = W + (64 + hh * 32 + quad * 8) * 64 + t * 16 + l15;   // Wj rows 64..127
        half8 bi, bj;
#pragma unroll
        for (int x = 0; x < 8; ++x) { bi[x] = (_Float16)wi[x * 64]; bj[x] = (_Float16)wj[x * 64]; }
        pif = __builtin_amdgcn_mfma_f32_16x16x32_f16(hi[hh], bi, pif, 0, 0, 0);
        pjf = __builtin_amdgcn_mfma_f32_16x16x32_f16(hj[hh], bj, pjf, 0, 0, 0);
      }
#pragma unroll
      for (int r = 0; r < 4; ++r) pj[br][t][r] = pjf[r];
      // C-layout holds Pi[i0b+quad*4+r][t*16+l15]; wave w needs rows i0b+w*4+ii,
      // which live at lane w*16+l15, reg r=ii -> pure lane broadcast.
#pragma unroll
      for (int ii = 0; ii < 4; ++ii)
        pia_all[br][t][ii] = __shfl(pif[ii], w * 16 + l15);
    }
  }

  // ---- Loop-invariant We B-fragments (rows 128..191): wf[branch][ltile][khalf] ----
  half8 wf[2][4][2];
#pragma unroll
  for (int br = 0; br < 2; ++br)
#pragma unroll
    for (int t = 0; t < 4; ++t)
#pragma unroll
      for (int hh = 0; hh < 2; ++hh) {
        const float* wsrc = Wptr[br] + (128 + hh * 32 + quad * 8) * 64 + t * 16 + l15;
        half8 v;
#pragma unroll
        for (int x = 0; x < 8; ++x) v[x] = (_Float16)wsrc[x * 64];
        wf[br][t][hh] = v;
      }

  float biasv[2][4];
#pragma unroll
  for (int t = 0; t < 4; ++t) {
    biasv[0][t] = ba[t * 16 + l15];
    biasv[1][t] = bn[t * 16 + l15];
  }

  float acc[4][4];
#pragma unroll
  for (int t = 0; t < 4; ++t)
#pragma unroll
    for (int r = 0; r < 4; ++r) acc[t][r] = 0.f;

  // ---- Main loop over this wave's 4 i's ----
#pragma unroll
  for (int ii = 0; ii < 4; ++ii) {
    const int i = i0 + ii;
    // A-fragment: row j0+l15 of E tile, e = quad*8+x (+32)
    const float* erow = E + ((size_t)((b * 128 + i) * 128 + j0 + l15)) * 64 + quad * 8;
    half8 a0 = cvt2(*reinterpret_cast<const float4*>(erow),
                    *reinterpret_cast<const float4*>(erow + 4));
    half8 a1 = cvt2(*reinterpret_cast<const float4*>(erow + 32),
                    *reinterpret_cast<const float4*>(erow + 36));

    const float4 av4 = *reinterpret_cast<const float4*>(
        A + (b * 128 + i) * 128 + j0 + quad * 4);
    const float av[4] = {av4.x, av4.y, av4.z, av4.w};

#pragma unroll
    for (int t = 0; t < 4; ++t) {
      floatx4 z = {0.f, 0.f, 0.f, 0.f};
      floatx4 pa = __builtin_amdgcn_mfma_f32_16x16x32_f16(a0, wf[0][t][0], z, 0, 0, 0);
      pa = __builtin_amdgcn_mfma_f32_16x16x32_f16(a1, wf[0][t][1], pa, 0, 0, 0);
      floatx4 pn = __builtin_amdgcn_mfma_f32_16x16x32_f16(a0, wf[1][t][0], z, 0, 0, 0);
      pn = __builtin_amdgcn_mfma_f32_16x16x32_f16(a1, wf[1][t][1], pn, 0, 0, 0);
#pragma unroll
      for (int r = 0; r < 4; ++r) {
        float att = av[r] * (pa[r] + pia_all[0][t][ii] + pj[0][t][r]) + biasv[0][t];
        float cnv = av[r] * (pn[r] + pia_all[1][t][ii] + pj[1][t][r]) + biasv[1][t];
        float ex = __expf(-att);
        float sig = __builtin_amdgcn_rcpf(1.0f + ex);
        acc[t][r] += sig * fmaxf(cnv, 0.f);
      }
    }
  }

  // ---- Epilogue: intra-block reduce (4 waves), then 8-contender atomics ----
  __shared__ float red[4][16][64];
#pragma unroll
  for (int t = 0; t < 4; ++t)
#pragma unroll
    for (int r = 0; r < 4; ++r)
      red[w][quad * 4 + r][t * 16 + l15] = acc[t][r];
  __syncthreads();

  const int tid = threadIdx.x;
#pragma unroll
  for (int k = 0; k < 4; ++k) {
    int idx = k * 256 + tid;       // 0..1023 over the 16x64 out tile
    int jl = idx >> 6;
    int l = idx & 63;
    float s = red[0][jl][l] + red[1][jl][l] + red[2][jl][l] + red[3][jl][l];
    atomicAdd(out + (b * 128 + j0 + jl) * 64 + l, s);
  }
}

extern "C" void kernel_launch(void* const* d_in, const int* in_sizes, int n_in,
                              void* d_out, int out_size, void* d_ws, size_t ws_size,
                              hipStream_t stream) {
  const float* H = (const float*)d_in[0];
  const float* A = (const float*)d_in[1];
  const float* E = (const float*)d_in[2];
  const float* Wa = (const float*)d_in[3];
  const float* Wn = (const float*)d_in[4];
  const float* ba = (const float*)d_in[5];
  const float* bn = (const float*)d_in[6];
  float* out = (float*)d_out;

  hipMemsetAsync(d_out, 0, (size_t)out_size * sizeof(float), stream);
  amp_fused<<<512, 256, 0, stream>>>(H, A, E, Wa, Wn, ba, bn, out);
}